// Round 1
// baseline (1516.990 us; speedup 1.0000x reference)
//
#include <hip/hip_runtime.h>

#define NB 256
#define NT 1024
#define NC 128
#define ND 64

typedef _Float16 f16x2_t __attribute__((ext_vector_type(2)));

__device__ __forceinline__ float fexp2(float x){
#if __has_builtin(__builtin_amdgcn_exp2f)
  return __builtin_amdgcn_exp2f(x);
#else
  return exp2f(x);
#endif
}
__device__ __forceinline__ float frcp_(float x){
#if __has_builtin(__builtin_amdgcn_rcpf)
  return __builtin_amdgcn_rcpf(x);
#else
  return 1.0f / x;
#endif
}
__device__ __forceinline__ float sigmoid_f(float x){
  return frcp_(1.0f + fexp2(-1.4426950408889634f * x));
}
__device__ __forceinline__ float tanh_f(float x){
  return 1.0f - 2.0f * frcp_(fexp2(2.8853900817779268f * x) + 1.0f);
}
// exp(CLAMP*0.636*atan(s/CLAMP)) with CLAMP=5 -> exp(3.18*atan(0.2*s))
__device__ __forceinline__ float e_func(float s){
  float u = 0.2f * s;
  float au = fabsf(u);
  bool inv = au > 1.0f;
  float v = inv ? frcp_(au) : au;
  float v2 = v * v;
  float pp = -0.0117212f;
  pp = pp * v2 + 0.05265332f;
  pp = pp * v2 - 0.11643287f;
  pp = pp * v2 + 0.19354346f;
  pp = pp * v2 - 0.33262347f;
  pp = pp * v2 + 0.99997726f;
  float at = pp * v;
  if (inv) at = 1.5707963267948966f - at;
  at = __builtin_copysignf(at, u);
  return fexp2(4.5877702301963f * at); // 3.18 * log2(e) * atan
}

__device__ __forceinline__ unsigned packh(float a, float b){
  union { _Float16 h[2]; unsigned u; } v;
  v.h[0] = (_Float16)a; v.h[1] = (_Float16)b;
  return v.u;
}
__device__ __forceinline__ float fdot2u(unsigned a, unsigned b, float c){
#if __has_builtin(__builtin_amdgcn_fdot2)
  return __builtin_amdgcn_fdot2(__builtin_bit_cast(f16x2_t, a), __builtin_bit_cast(f16x2_t, b), c, false);
#else
  f16x2_t av = __builtin_bit_cast(f16x2_t, a);
  f16x2_t bv = __builtin_bit_cast(f16x2_t, b);
  return c + (float)av[0]*(float)bv[0] + (float)av[1]*(float)bv[1];
#endif
}
__device__ __forceinline__ void load16(unsigned* d, const unsigned* s){
  uint4 a = reinterpret_cast<const uint4*>(s)[0];
  uint4 b = reinterpret_cast<const uint4*>(s)[1];
  uint4 c = reinterpret_cast<const uint4*>(s)[2];
  uint4 e = reinterpret_cast<const uint4*>(s)[3];
  d[0]=a.x; d[1]=a.y; d[2]=a.z; d[3]=a.w;
  d[4]=b.x; d[5]=b.y; d[6]=b.z; d[7]=b.w;
  d[8]=c.x; d[9]=c.y; d[10]=c.z; d[11]=c.w;
  d[12]=e.x; d[13]=e.y; d[14]=e.z; d[15]=e.w;
}

#define DOT16(acc, V, W) do { _Pragma("unroll") for (int kk=0; kk<16; ++kk) acc = fdot2u((V)[kk], (W)[kk], acc); } while(0)

__global__ __launch_bounds__(256, 1)
void glow_gru_kernel(const float* __restrict__ x,
                     const float* __restrict__ Wx1, const float* __restrict__ Wh1,
                     const float* __restrict__ bx1, const float* __restrict__ bh1,
                     const float* __restrict__ Wo1, const float* __restrict__ bo1,
                     const float* __restrict__ Wx2, const float* __restrict__ Wh2,
                     const float* __restrict__ bx2, const float* __restrict__ bh2,
                     const float* __restrict__ Wo2, const float* __restrict__ bo2,
                     float* __restrict__ out)
{
  // per-step partials: [half][unit] ; units: 0..191 = gh cols, 192..383 = gx cols
  __shared__ float p[2][384];
  __shared__ float h1f[ND], h2f[ND];
  __shared__ __align__(16) unsigned h1p[32], h2p[32], y1p[32];
  __shared__ float xf[2][NC];
  __shared__ __align__(16) unsigned x2p[2][32];
  __shared__ float br1[128], bn1x[ND], bn1h[ND], bo1s[128];
  __shared__ float br2[128], bn2x[ND], bn2h[ND], bo2s[128];

  const int l = threadIdx.x;
  const int q = l & 127;      // column group
  const int half = l >> 7;    // k-half: 0 -> k in [0,32), 1 -> k in [32,64)
  const int b = blockIdx.x;

  // ---- init biases / state / x(0) staging ----
  if (l < 128){
    br1[l]  = bx1[l] + bh1[l];
    br2[l]  = bx2[l] + bh2[l];
    bo1s[l] = bo1[l];
    bo2s[l] = bo2[l];
  } else {
    int i = l - 128;
    if (i < 64){
      bn1x[i] = bx1[128+i]; bn1h[i] = bh1[128+i];
      bn2x[i] = bx2[128+i]; bn2h[i] = bh2[128+i];
      h1f[i] = 0.f; h2f[i] = 0.f;
    } else {
      int j = i - 64;
      if (j < 32){ h1p[j] = 0u; h2p[j] = 0u; }
    }
  }
  if (l < 128){
    float v = x[(b*NT + 0)*NC + l];
    xf[0][l] = v;
    if (l >= 64) reinterpret_cast<_Float16*>(x2p[0])[l-64] = (_Float16)v;
  }

  // ---- load weights into registers (f16 pairs along k) ----
  // Phase A (GRU2 gates): unit u=q+m*128; u<192 -> Wh2 col u (input h2), else Wx2 col u-192 (input x2)
  // Phase E (GRU1 gates): same with Wh1 / Wx1 (input y1)
  // Phase C: Wo2 col q ; Phase G: Wo1 col q
  unsigned wA[3][16], wE[3][16], wC16[16], wG16[16];
  #pragma unroll
  for (int m = 0; m < 3; ++m){
    const int u = q + m*128;
    const float* MA; int ca;
    const float* ME; int ce;
    if (u < 192){ MA = Wh2; ca = u; ME = Wh1; ce = u; }
    else        { MA = Wx2; ca = u - 192; ME = Wx1; ce = u - 192; }
    #pragma unroll
    for (int k2 = 0; k2 < 16; ++k2){
      const int k = half*32 + 2*k2;
      wA[m][k2] = packh(MA[k*192 + ca], MA[(k+1)*192 + ca]);
      wE[m][k2] = packh(ME[k*192 + ce], ME[(k+1)*192 + ce]);
    }
  }
  #pragma unroll
  for (int k2 = 0; k2 < 16; ++k2){
    const int k = half*32 + 2*k2;
    wC16[k2] = packh(Wo2[k*128 + q], Wo2[(k+1)*128 + q]);
    wG16[k2] = packh(Wo1[k*128 + q], Wo1[(k+1)*128 + q]);
  }
  __syncthreads();

  float xreg = 0.f;
  const long xbase = (long)b * NT * NC;
  float* outb = out + (long)b * NT * NC;

  for (int t = 0; t < NT; ++t){
    const int buf = t & 1, nbuf = buf ^ 1;
    // prefetch x(t+1) (lands in phase H, ~full step of latency cover)
    if (t + 1 < NT && l < 128) xreg = x[xbase + (long)(t+1)*NC + l];

    // ---- Phase A: gh2 (h2p) / gx2 (x2p[buf]) ----
    {
      unsigned hv[16], xv[16];
      load16(hv, h2p + half*16);
      load16(xv, x2p[buf] + half*16);
      #pragma unroll
      for (int m = 0; m < 3; ++m){
        float a = 0.f;
        if (q + m*128 < 192) { DOT16(a, hv, wA[m]); }
        else                 { DOT16(a, xv, wA[m]); }
        p[half][q + m*128] = a;
      }
    }
    __syncthreads();
    // ---- Phase B: GRU2 activations (lanes 0..63) ----
    if (l < ND){
      const int i = l;
      float rh = p[0][i]       + p[1][i];
      float zh = p[0][64+i]    + p[1][64+i];
      float nh = p[0][128+i]   + p[1][128+i] + bn2h[i];
      float rx = p[0][192+i]   + p[1][192+i];
      float zx = p[0][256+i]   + p[1][256+i];
      float nx = p[0][320+i]   + p[1][320+i] + bn2x[i];
      float r = sigmoid_f(rx + rh + br2[i]);
      float z = sigmoid_f(zx + zh + br2[64+i]);
      float n = tanh_f(nx + r*nh);
      float hn = (1.0f - z)*n + z*h2f[i];
      h2f[i] = hn;
      reinterpret_cast<_Float16*>(h2p)[i] = (_Float16)hn;
    }
    __syncthreads();
    // ---- Phase C: r2 = h2n @ Wo2 ----
    {
      unsigned hv[16];
      load16(hv, h2p + half*16);
      float a = 0.f; DOT16(a, hv, wC16);
      p[half][q] = a;
    }
    __syncthreads();
    // ---- Phase D: y1 = e(s2v)*x1 + t2 ----
    if (l < ND){
      const int i = l;
      float s2v = p[0][i]    + p[1][i]    + bo2s[i];
      float t2  = p[0][64+i] + p[1][64+i] + bo2s[64+i];
      float y1 = e_func(s2v) * xf[buf][i] + t2;
      outb[(long)t*NC + i] = y1;
      reinterpret_cast<_Float16*>(y1p)[i] = (_Float16)y1;
    }
    __syncthreads();
    // ---- Phase E: gh1 (h1p) / gx1 (y1p) ----
    {
      unsigned hv[16], yv[16];
      load16(hv, h1p + half*16);
      load16(yv, y1p + half*16);
      #pragma unroll
      for (int m = 0; m < 3; ++m){
        float a = 0.f;
        if (q + m*128 < 192) { DOT16(a, hv, wE[m]); }
        else                 { DOT16(a, yv, wE[m]); }
        p[half][q + m*128] = a;
      }
    }
    __syncthreads();
    // ---- Phase F: GRU1 activations ----
    if (l < ND){
      const int i = l;
      float rh = p[0][i]       + p[1][i];
      float zh = p[0][64+i]    + p[1][64+i];
      float nh = p[0][128+i]   + p[1][128+i] + bn1h[i];
      float rx = p[0][192+i]   + p[1][192+i];
      float zx = p[0][256+i]   + p[1][256+i];
      float nx = p[0][320+i]   + p[1][320+i] + bn1x[i];
      float r = sigmoid_f(rx + rh + br1[i]);
      float z = sigmoid_f(zx + zh + br1[64+i]);
      float n = tanh_f(nx + r*nh);
      float hn = (1.0f - z)*n + z*h1f[i];
      h1f[i] = hn;
      reinterpret_cast<_Float16*>(h1p)[i] = (_Float16)hn;
    }
    __syncthreads();
    // ---- Phase G: r1 = h1n @ Wo1 ----
    {
      unsigned hv[16];
      load16(hv, h1p + half*16);
      float a = 0.f; DOT16(a, hv, wG16);
      p[half][q] = a;
    }
    __syncthreads();
    // ---- Phase H: y2 = e(s1v)*x2 + t1 ; stage x(t+1) ----
    if (l < ND){
      const int i = l;
      float s1v = p[0][i]    + p[1][i]    + bo1s[i];
      float t1  = p[0][64+i] + p[1][64+i] + bo1s[64+i];
      float y2 = e_func(s1v) * xf[buf][64+i] + t1;
      outb[(long)t*NC + 64 + i] = y2;
    }
    if (t + 1 < NT && l < 128){
      xf[nbuf][l] = xreg;
      if (l >= 64) reinterpret_cast<_Float16*>(x2p[nbuf])[l-64] = (_Float16)xreg;
    }
    __syncthreads();
  }
}

extern "C" void kernel_launch(void* const* d_in, const int* in_sizes, int n_in,
                              void* d_out, int out_size, void* d_ws, size_t ws_size,
                              hipStream_t stream) {
  const float* x   = (const float*)d_in[0];
  const float* Wx1 = (const float*)d_in[1];
  const float* Wh1 = (const float*)d_in[2];
  const float* bx1 = (const float*)d_in[3];
  const float* bh1 = (const float*)d_in[4];
  const float* Wo1 = (const float*)d_in[5];
  const float* bo1 = (const float*)d_in[6];
  const float* Wx2 = (const float*)d_in[7];
  const float* Wh2 = (const float*)d_in[8];
  const float* bx2 = (const float*)d_in[9];
  const float* bh2 = (const float*)d_in[10];
  const float* Wo2 = (const float*)d_in[11];
  const float* bo2 = (const float*)d_in[12];
  float* out = (float*)d_out;

  hipLaunchKernelGGL(glow_gru_kernel, dim3(NB), dim3(256), 0, stream,
                     x, Wx1, Wh1, bx1, bh1, Wo1, bo1,
                     Wx2, Wh2, bx2, bh2, Wo2, bo2, out);
}

// Round 2
// 933.327 us; speedup vs baseline: 1.6254x; 1.6254x over previous
//
#include <hip/hip_runtime.h>

#define NB 256
#define NT 1024
#define NC 128
#define ND 64

typedef _Float16 f16x2_t __attribute__((ext_vector_type(2)));

__device__ __forceinline__ float fexp2(float x){
#if __has_builtin(__builtin_amdgcn_exp2f)
  return __builtin_amdgcn_exp2f(x);
#else
  return exp2f(x);
#endif
}
__device__ __forceinline__ float frcp_(float x){
#if __has_builtin(__builtin_amdgcn_rcpf)
  return __builtin_amdgcn_rcpf(x);
#else
  return 1.0f / x;
#endif
}
__device__ __forceinline__ float sigmoid_f(float x){
  return frcp_(1.0f + fexp2(-1.4426950408889634f * x));
}
__device__ __forceinline__ float tanh_f(float x){
  return 1.0f - 2.0f * frcp_(fexp2(2.8853900817779268f * x) + 1.0f);
}
// exp(CLAMP*0.636*atan(s/CLAMP)) with CLAMP=5 -> exp(3.18*atan(0.2*s))
__device__ __forceinline__ float e_func(float s){
  float u = 0.2f * s;
  float au = fabsf(u);
  bool inv = au > 1.0f;
  float v = inv ? frcp_(au) : au;
  float v2 = v * v;
  float pp = -0.0117212f;
  pp = pp * v2 + 0.05265332f;
  pp = pp * v2 - 0.11643287f;
  pp = pp * v2 + 0.19354346f;
  pp = pp * v2 - 0.33262347f;
  pp = pp * v2 + 0.99997726f;
  float at = pp * v;
  if (inv) at = 1.5707963267948966f - at;
  at = __builtin_copysignf(at, u);
  return fexp2(4.5877702301963f * at); // 3.18 * log2(e) * atan
}

__device__ __forceinline__ unsigned packh(float a, float b){
  union { _Float16 h[2]; unsigned u; } v;
  v.h[0] = (_Float16)a; v.h[1] = (_Float16)b;
  return v.u;
}
__device__ __forceinline__ float fdot2u(unsigned a, unsigned b, float c){
#if __has_builtin(__builtin_amdgcn_fdot2)
  return __builtin_amdgcn_fdot2(__builtin_bit_cast(f16x2_t, a), __builtin_bit_cast(f16x2_t, b), c, false);
#else
  f16x2_t av = __builtin_bit_cast(f16x2_t, a);
  f16x2_t bv = __builtin_bit_cast(f16x2_t, b);
  return c + (float)av[0]*(float)bv[0] + (float)av[1]*(float)bv[1];
#endif
}
__device__ __forceinline__ void load16(unsigned* d, const unsigned* s){
  uint4 a = reinterpret_cast<const uint4*>(s)[0];
  uint4 b = reinterpret_cast<const uint4*>(s)[1];
  uint4 c = reinterpret_cast<const uint4*>(s)[2];
  uint4 e = reinterpret_cast<const uint4*>(s)[3];
  d[0]=a.x; d[1]=a.y; d[2]=a.z; d[3]=a.w;
  d[4]=b.x; d[5]=b.y; d[6]=b.z; d[7]=b.w;
  d[8]=c.x; d[9]=c.y; d[10]=c.z; d[11]=c.w;
  d[12]=e.x; d[13]=e.y; d[14]=e.z; d[15]=e.w;
}

#define DOT16(acc, V, W) do { _Pragma("unroll") for (int kk=0; kk<16; ++kk) acc = fdot2u((V)[kk], (W)[kk], acc); } while(0)

// Partials layout (unit u, halves adjacent): p[u][half]
//   u in [0,384)    : GRU2 gates. u<192 -> gh2 col u ; u>=192 -> gx2 col u-192
//   u in [384,768)  : GRU1 gates. (u-384)<192 -> gh1 ; else gx1
//   u in [768,896)  : Wo2 col u-768
//   u in [896,1024) : Wo1 col u-896
__global__ __launch_bounds__(256, 1)
void glow_gru_kernel(const float* __restrict__ x,
                     const float* __restrict__ Wx1, const float* __restrict__ Wh1,
                     const float* __restrict__ bx1, const float* __restrict__ bh1,
                     const float* __restrict__ Wo1, const float* __restrict__ bo1,
                     const float* __restrict__ Wx2, const float* __restrict__ Wh2,
                     const float* __restrict__ bx2, const float* __restrict__ bh2,
                     const float* __restrict__ Wo2, const float* __restrict__ bo2,
                     float* __restrict__ out)
{
  __shared__ __align__(8) float p[1024][2];
  __shared__ __align__(16) unsigned h2p[32], h1p[32], y1p[32], x2p[32];
  __shared__ float xf[8][NC];

  const int l = threadIdx.x;
  const int q = l & 127;      // dot column group
  const int half = l >> 7;    // k-half for dots
  const int wv = l >> 6;      // wave id (alpha-phase role)
  const int i = l & 63;       // unit within role
  const int b = blockIdx.x;

  // ---- weights into registers (f16 pairs along k) ----
  unsigned wA[3][16], wE[3][16], wC16[16], wG16[16];
  #pragma unroll
  for (int m = 0; m < 3; ++m){
    const int u = q + m*128;
    const float* MA; int ca;
    const float* ME; int ce;
    if (u < 192){ MA = Wh2; ca = u; ME = Wh1; ce = u; }
    else        { MA = Wx2; ca = u - 192; ME = Wx1; ce = u - 192; }
    #pragma unroll
    for (int k2 = 0; k2 < 16; ++k2){
      const int k = half*32 + 2*k2;
      wA[m][k2] = packh(MA[k*192 + ca], MA[(k+1)*192 + ca]);
      wE[m][k2] = packh(ME[k*192 + ce], ME[(k+1)*192 + ce]);
    }
  }
  #pragma unroll
  for (int k2 = 0; k2 < 16; ++k2){
    const int k = half*32 + 2*k2;
    wC16[k2] = packh(Wo2[k*128 + q], Wo2[(k+1)*128 + q]);
    wG16[k2] = packh(Wo1[k*128 + q], Wo1[(k+1)*128 + q]);
  }

  // ---- per-lane biases (meaning depends on wave role) ----
  float bR = 0.f, bZ = 0.f, bNX = 0.f, bNH = 0.f;
  if (wv == 0){ bR = bx2[i]+bh2[i]; bZ = bx2[64+i]+bh2[64+i]; bNX = bx2[128+i]; bNH = bh2[128+i]; }
  else if (wv == 1){ bR = bo2[i]; bZ = bo2[64+i]; }
  else if (wv == 2){ bR = bx1[i]+bh1[i]; bZ = bx1[64+i]+bh1[64+i]; bNX = bx1[128+i]; bNH = bh1[128+i]; }
  else { bR = bo1[i]; bZ = bo1[64+i]; }

  float hreg = 0.f;  // h2 state (wave0 lanes) / h1 state (wave2 lanes)

  // zero the f16 packs (covers warm-up iterations)
  if (l < 32){ h2p[l] = 0u; h1p[l] = 0u; y1p[l] = 0u; x2p[l] = 0u; }

  const long xbase = (long)b * NT * NC;
  float xr0 = 0.f, xr1 = 0.f;
  if (l < 128){ xr0 = x[xbase + l]; xr1 = x[xbase + NC + l]; }
  __syncthreads();

  for (int j = -1; j <= NT + 2; ++j){
    // ================= Phase alpha =================
    // stage x(j+1): xr0 holds x(j+1)
    if (l < 128 && (j + 1) < NT){
      xf[(j+1) & 7][l] = xr0;
      if (l >= 64) reinterpret_cast<_Float16*>(x2p)[l-64] = (_Float16)xr0;
    }
    if (wv == 0){
      // act2(j): consume gh2/gx2 partials -> h2n
      if (j >= 0 && j < NT){
        float2 vrh = *(const float2*)p[i];
        float2 vzh = *(const float2*)p[64+i];
        float2 vnh = *(const float2*)p[128+i];
        float2 vrx = *(const float2*)p[192+i];
        float2 vzx = *(const float2*)p[256+i];
        float2 vnx = *(const float2*)p[320+i];
        float r = sigmoid_f(vrx.x+vrx.y + vrh.x+vrh.y + bR);
        float z = sigmoid_f(vzx.x+vzx.y + vzh.x+vzh.y + bZ);
        float n = tanh_f(vnx.x+vnx.y + bNX + r*(vnh.x+vnh.y + bNH));
        hreg = (1.0f - z)*n + z*hreg;
        reinterpret_cast<_Float16*>(h2p)[i] = (_Float16)hreg;
      }
    } else if (wv == 1){
      // y1(j-1): consume Wo2 partials
      const int t = j - 1;
      if (t >= 0 && t < NT){
        float2 vs = *(const float2*)p[768+i];
        float2 vt = *(const float2*)p[832+i];
        float s2v = vs.x + vs.y + bR;
        float t2  = vt.x + vt.y + bZ;
        float y1 = e_func(s2v) * xf[t & 7][i] + t2;
        out[xbase + (long)t*NC + i] = y1;
        reinterpret_cast<_Float16*>(y1p)[i] = (_Float16)y1;
      }
    } else if (wv == 2){
      // act1(j-2): consume gh1/gx1 partials -> h1n
      const int t = j - 2;
      if (t >= 0 && t < NT){
        float2 vrh = *(const float2*)p[384+i];
        float2 vzh = *(const float2*)p[448+i];
        float2 vnh = *(const float2*)p[512+i];
        float2 vrx = *(const float2*)p[576+i];
        float2 vzx = *(const float2*)p[640+i];
        float2 vnx = *(const float2*)p[704+i];
        float r = sigmoid_f(vrx.x+vrx.y + vrh.x+vrh.y + bR);
        float z = sigmoid_f(vzx.x+vzx.y + vzh.x+vzh.y + bZ);
        float n = tanh_f(vnx.x+vnx.y + bNX + r*(vnh.x+vnh.y + bNH));
        hreg = (1.0f - z)*n + z*hreg;
        reinterpret_cast<_Float16*>(h1p)[i] = (_Float16)hreg;
      }
    } else {
      // y2(j-3): consume Wo1 partials
      const int t = j - 3;
      if (t >= 0 && t < NT){
        float2 vs = *(const float2*)p[896+i];
        float2 vt = *(const float2*)p[960+i];
        float s1v = vs.x + vs.y + bR;
        float t1  = vt.x + vt.y + bZ;
        float y2 = e_func(s1v) * xf[t & 7][64+i] + t1;
        out[xbase + (long)t*NC + 64 + i] = y2;
      }
    }
    // advance x prefetch pipeline (2 deep)
    if (l < 128){
      xr0 = xr1;
      if ((j + 3) < NT) xr1 = x[xbase + (long)(j+3)*NC + l];
    }
    __syncthreads();
    if (j == NT + 2) break;

    // ================= Phase beta: all 8 half-matvecs =================
    {
      unsigned h2v[16], x2v[16], h1v[16], y1v[16];
      load16(h2v, h2p + half*16);
      load16(x2v, x2p + half*16);
      load16(h1v, h1p + half*16);
      load16(y1v, y1p + half*16);
      // GRU2 gates: gh2(j+1) / gx2(j+1)
      #pragma unroll
      for (int m = 0; m < 3; ++m){
        const int u = q + m*128;
        float a = 0.f;
        if (u < 192) { DOT16(a, h2v, wA[m]); }
        else         { DOT16(a, x2v, wA[m]); }
        p[u][half] = a;
      }
      // Wo2(j)
      { float a = 0.f; DOT16(a, h2v, wC16); p[768+q][half] = a; }
      // GRU1 gates: gh1(j-1) / gx1(j-1)
      #pragma unroll
      for (int m = 0; m < 3; ++m){
        const int u = q + m*128;
        float a = 0.f;
        if (u < 192) { DOT16(a, h1v, wE[m]); }
        else         { DOT16(a, y1v, wE[m]); }
        p[384+u][half] = a;
      }
      // Wo1(j-2)
      { float a = 0.f; DOT16(a, h1v, wG16); p[896+q][half] = a; }
    }
    __syncthreads();
  }
}

extern "C" void kernel_launch(void* const* d_in, const int* in_sizes, int n_in,
                              void* d_out, int out_size, void* d_ws, size_t ws_size,
                              hipStream_t stream) {
  const float* x   = (const float*)d_in[0];
  const float* Wx1 = (const float*)d_in[1];
  const float* Wh1 = (const float*)d_in[2];
  const float* bx1 = (const float*)d_in[3];
  const float* bh1 = (const float*)d_in[4];
  const float* Wo1 = (const float*)d_in[5];
  const float* bo1 = (const float*)d_in[6];
  const float* Wx2 = (const float*)d_in[7];
  const float* Wh2 = (const float*)d_in[8];
  const float* bx2 = (const float*)d_in[9];
  const float* bh2 = (const float*)d_in[10];
  const float* Wo2 = (const float*)d_in[11];
  const float* bo2 = (const float*)d_in[12];
  float* out = (float*)d_out;

  hipLaunchKernelGGL(glow_gru_kernel, dim3(NB), dim3(256), 0, stream,
                     x, Wx1, Wh1, bx1, bh1, Wo1, bo1,
                     Wx2, Wh2, bx2, bh2, Wo2, bo2, out);
}

// Round 3
// 729.391 us; speedup vs baseline: 2.0798x; 1.2796x over previous
//
#include <hip/hip_runtime.h>

#define NB 256
#define NT 1024
#define NC 128
#define ND 64

typedef _Float16 f16x2_t __attribute__((ext_vector_type(2)));

__device__ __forceinline__ float fexp2(float x){
#if __has_builtin(__builtin_amdgcn_exp2f)
  return __builtin_amdgcn_exp2f(x);
#else
  return exp2f(x);
#endif
}
__device__ __forceinline__ float frcp_(float x){
#if __has_builtin(__builtin_amdgcn_rcpf)
  return __builtin_amdgcn_rcpf(x);
#else
  return 1.0f / x;
#endif
}
__device__ __forceinline__ float sigmoid_f(float x){
  return frcp_(1.0f + fexp2(-1.4426950408889634f * x));
}
__device__ __forceinline__ float tanh_f(float x){
  return 1.0f - 2.0f * frcp_(fexp2(2.8853900817779268f * x) + 1.0f);
}
// exp(CLAMP*0.636*atan(s/CLAMP)) with CLAMP=5 -> exp(3.18*atan(0.2*s))
__device__ __forceinline__ float e_func(float s){
  float u = 0.2f * s;
  float au = fabsf(u);
  bool inv = au > 1.0f;
  float v = inv ? frcp_(au) : au;
  float v2 = v * v;
  float pp = -0.0117212f;
  pp = pp * v2 + 0.05265332f;
  pp = pp * v2 - 0.11643287f;
  pp = pp * v2 + 0.19354346f;
  pp = pp * v2 - 0.33262347f;
  pp = pp * v2 + 0.99997726f;
  float at = pp * v;
  if (inv) at = 1.5707963267948966f - at;
  at = __builtin_copysignf(at, u);
  return fexp2(4.5877702301963f * at); // 3.18 * log2(e) * atan
}

__device__ __forceinline__ unsigned packh(float a, float b){
  union { _Float16 h[2]; unsigned u; } v;
  v.h[0] = (_Float16)a; v.h[1] = (_Float16)b;
  return v.u;
}
__device__ __forceinline__ float fdot2u(unsigned a, unsigned b, float c){
#if __has_builtin(__builtin_amdgcn_fdot2)
  return __builtin_amdgcn_fdot2(__builtin_bit_cast(f16x2_t, a), __builtin_bit_cast(f16x2_t, b), c, false);
#else
  f16x2_t av = __builtin_bit_cast(f16x2_t, a);
  f16x2_t bv = __builtin_bit_cast(f16x2_t, b);
  return c + (float)av[0]*(float)bv[0] + (float)av[1]*(float)bv[1];
#endif
}
__device__ __forceinline__ void load16(unsigned* d, const unsigned* s){
  uint4 a = reinterpret_cast<const uint4*>(s)[0];
  uint4 b = reinterpret_cast<const uint4*>(s)[1];
  uint4 c = reinterpret_cast<const uint4*>(s)[2];
  uint4 e = reinterpret_cast<const uint4*>(s)[3];
  d[0]=a.x; d[1]=a.y; d[2]=a.z; d[3]=a.w;
  d[4]=b.x; d[5]=b.y; d[6]=b.z; d[7]=b.w;
  d[8]=c.x; d[9]=c.y; d[10]=c.z; d[11]=c.w;
  d[12]=e.x; d[13]=e.y; d[14]=e.z; d[15]=e.w;
}

#define DOT16(acc, V, W) do { _Pragma("unroll") for (int kk=0; kk<16; ++kk) acc = fdot2u((V)[kk], (W)[kk], acc); } while(0)

// Partials plane layout (conflict-free): p[half][unit]
//   unit in [0,384)    : GRU2 gates. <192 -> gh2 ; >=192 -> gx2 (col-192)
//   unit in [384,768)  : GRU1 gates (same split)
//   unit in [768,896)  : Wo2
//   unit in [896,1024) : Wo1
__global__ __launch_bounds__(512, 1)
void glow_gru_kernel(const float* __restrict__ x,
                     const float* __restrict__ Wx1, const float* __restrict__ Wh1,
                     const float* __restrict__ bx1, const float* __restrict__ bh1,
                     const float* __restrict__ Wo1, const float* __restrict__ bo1,
                     const float* __restrict__ Wx2, const float* __restrict__ Wh2,
                     const float* __restrict__ bx2, const float* __restrict__ bh2,
                     const float* __restrict__ Wo2, const float* __restrict__ bo2,
                     float* __restrict__ out)
{
  __shared__ float p[2][1024];
  __shared__ __align__(16) unsigned h2p[32], h1p[32], y1p[32], x2p[32];
  __shared__ float xf[8][NC];

  const int l = threadIdx.x;      // 0..511
  const int g = l >> 8;           // 0: GRU2-side dots, 1: GRU1-side dots
  const int w2 = (l >> 6) & 3;    // wave within group
  const int half = w2 >> 1;       // k-half (0: k<32, 1: k>=32)
  const int role = w2 & 1;        // 0: {WH r,z,n + WO s} ; 1: {WO t + WX r,z,n}
  const int i = l & 63;
  const int wv = l >> 6;          // global wave id (alpha roles)
  const int b = blockIdx.x;

  // ---- weights into registers: 4 slots x 16 f16-pair dwords = 64 VGPR ----
  const float* WH = g ? Wh1 : Wh2;
  const float* WX = g ? Wx1 : Wx2;
  const float* WO = g ? Wo1 : Wo2;
  unsigned ws[4][16];
  #pragma unroll
  for (int k2 = 0; k2 < 16; ++k2){
    const int k = half*32 + 2*k2;
    if (role == 0){
      ws[0][k2] = packh(WH[k*192 + i],       WH[(k+1)*192 + i]);
      ws[1][k2] = packh(WH[k*192 + 64 + i],  WH[(k+1)*192 + 64 + i]);
      ws[2][k2] = packh(WH[k*192 + 128 + i], WH[(k+1)*192 + 128 + i]);
      ws[3][k2] = packh(WO[k*128 + i],       WO[(k+1)*128 + i]);
    } else {
      ws[0][k2] = packh(WO[k*128 + 64 + i],  WO[(k+1)*128 + 64 + i]);
      ws[1][k2] = packh(WX[k*192 + i],       WX[(k+1)*192 + i]);
      ws[2][k2] = packh(WX[k*192 + 64 + i],  WX[(k+1)*192 + 64 + i]);
      ws[3][k2] = packh(WX[k*192 + 128 + i], WX[(k+1)*192 + 128 + i]);
    }
  }

  // ---- per-lane biases for alpha roles (waves 0..3 only) ----
  float bR = 0.f, bZ = 0.f, bNX = 0.f, bNH = 0.f;
  if (wv == 0){ bR = bx2[i]+bh2[i]; bZ = bx2[64+i]+bh2[64+i]; bNX = bx2[128+i]; bNH = bh2[128+i]; }
  else if (wv == 1){ bR = bo2[i]; bZ = bo2[64+i]; }
  else if (wv == 2){ bR = bx1[i]+bh1[i]; bZ = bx1[64+i]+bh1[64+i]; bNX = bx1[128+i]; bNH = bh1[128+i]; }
  else if (wv == 3){ bR = bo1[i]; bZ = bo1[64+i]; }

  float hreg = 0.f;  // h2 (wave0) / h1 (wave2)

  if (l < 32){ h2p[l] = 0u; h1p[l] = 0u; y1p[l] = 0u; x2p[l] = 0u; }

  // x prefetch owned by waves 4-5 (alpha-idle)
  const long xbase = (long)b * NT * NC;
  const int xl = l - 256;         // valid for waves 4,5: 0..127
  float xr0 = 0.f, xr1 = 0.f;
  if (xl >= 0 && xl < 128){ xr0 = x[xbase + xl]; xr1 = x[xbase + NC + xl]; }
  __syncthreads();

  for (int j = -1; j <= NT + 2; ++j){
    // ================= Phase alpha =================
    if (wv == 0){
      // act2(j) -> h2n
      if (j >= 0 && j < NT){
        float rh = p[0][i]     + p[1][i];
        float zh = p[0][64+i]  + p[1][64+i];
        float nh = p[0][128+i] + p[1][128+i];
        float rx = p[0][192+i] + p[1][192+i];
        float zx = p[0][256+i] + p[1][256+i];
        float nx = p[0][320+i] + p[1][320+i];
        float r = sigmoid_f(rx + rh + bR);
        float z = sigmoid_f(zx + zh + bZ);
        float n = tanh_f(nx + bNX + r*(nh + bNH));
        hreg = (1.0f - z)*n + z*hreg;
        reinterpret_cast<_Float16*>(h2p)[i] = (_Float16)hreg;
      }
    } else if (wv == 1){
      // y1(j-1)
      const int t = j - 1;
      if (t >= 0 && t < NT){
        float s2v = p[0][768+i] + p[1][768+i] + bR;
        float t2  = p[0][832+i] + p[1][832+i] + bZ;
        float y1 = e_func(s2v) * xf[t & 7][i] + t2;
        out[xbase + (long)t*NC + i] = y1;
        reinterpret_cast<_Float16*>(y1p)[i] = (_Float16)y1;
      }
    } else if (wv == 2){
      // act1(j-2) -> h1n
      const int t = j - 2;
      if (t >= 0 && t < NT){
        float rh = p[0][384+i] + p[1][384+i];
        float zh = p[0][448+i] + p[1][448+i];
        float nh = p[0][512+i] + p[1][512+i];
        float rx = p[0][576+i] + p[1][576+i];
        float zx = p[0][640+i] + p[1][640+i];
        float nx = p[0][704+i] + p[1][704+i];
        float r = sigmoid_f(rx + rh + bR);
        float z = sigmoid_f(zx + zh + bZ);
        float n = tanh_f(nx + bNX + r*(nh + bNH));
        hreg = (1.0f - z)*n + z*hreg;
        reinterpret_cast<_Float16*>(h1p)[i] = (_Float16)hreg;
      }
    } else if (wv == 3){
      // y2(j-3)
      const int t = j - 3;
      if (t >= 0 && t < NT){
        float s1v = p[0][896+i] + p[1][896+i] + bR;
        float t1  = p[0][960+i] + p[1][960+i] + bZ;
        float y2 = e_func(s1v) * xf[t & 7][64+i] + t1;
        out[xbase + (long)t*NC + 64 + i] = y2;
      }
    } else if (xl >= 0 && xl < 128){
      // waves 4-5: stage x(j+1) and advance 2-deep prefetch
      if ((j + 1) < NT){
        xf[(j+1) & 7][xl] = xr0;
        if (xl >= 64) reinterpret_cast<_Float16*>(x2p)[xl-64] = (_Float16)xr0;
      }
      xr0 = xr1;
      if ((j + 3) < NT) xr1 = x[xbase + (long)(j+3)*NC + xl];
    }
    __syncthreads();
    if (j == NT + 2) break;

    // ================= Phase beta: 8 half-matvecs, wave-uniform operands ====
    {
      const int pb = g * 384;
      const int ob = 768 + g * 128;
      unsigned hv[16];
      load16(hv, (g ? h1p : h2p) + half*16);
      if (role == 0){
        float a0=0.f, a1=0.f, a2=0.f, a3=0.f;
        DOT16(a0, hv, ws[0]);
        DOT16(a1, hv, ws[1]);
        DOT16(a2, hv, ws[2]);
        DOT16(a3, hv, ws[3]);
        p[half][pb+i]      = a0;
        p[half][pb+64+i]   = a1;
        p[half][pb+128+i]  = a2;
        p[half][ob+i]      = a3;
      } else {
        unsigned ov[16];
        load16(ov, (g ? y1p : x2p) + half*16);
        float a0=0.f, a1=0.f, a2=0.f, a3=0.f;
        DOT16(a0, hv, ws[0]);
        DOT16(a1, ov, ws[1]);
        DOT16(a2, ov, ws[2]);
        DOT16(a3, ov, ws[3]);
        p[half][ob+64+i]   = a0;
        p[half][pb+192+i]  = a1;
        p[half][pb+256+i]  = a2;
        p[half][pb+320+i]  = a3;
      }
    }
    __syncthreads();
  }
}

extern "C" void kernel_launch(void* const* d_in, const int* in_sizes, int n_in,
                              void* d_out, int out_size, void* d_ws, size_t ws_size,
                              hipStream_t stream) {
  const float* x   = (const float*)d_in[0];
  const float* Wx1 = (const float*)d_in[1];
  const float* Wh1 = (const float*)d_in[2];
  const float* bx1 = (const float*)d_in[3];
  const float* bh1 = (const float*)d_in[4];
  const float* Wo1 = (const float*)d_in[5];
  const float* bo1 = (const float*)d_in[6];
  const float* Wx2 = (const float*)d_in[7];
  const float* Wh2 = (const float*)d_in[8];
  const float* bx2 = (const float*)d_in[9];
  const float* bh2 = (const float*)d_in[10];
  const float* Wo2 = (const float*)d_in[11];
  const float* bo2 = (const float*)d_in[12];
  float* out = (float*)d_out;

  hipLaunchKernelGGL(glow_gru_kernel, dim3(NB), dim3(512), 0, stream,
                     x, Wx1, Wh1, bx1, bh1, Wo1, bo1,
                     Wx2, Wh2, bx2, bh2, Wo2, bo2, out);
}